// Round 2
// 381.308 us; speedup vs baseline: 1.0248x; 1.0248x over previous
//
#include <hip/hip_runtime.h>

// Problem constants (from reference):
//   B=8, S=4, L=512, H=768  -> hidden (8, 2048, 768) fp32 (50 MB, L3-resident)
//   N_SPANS=4096, T_MAX=16, N_PAIRS=16384
//   reprs[s] = [first(768) | mean(768) | last(768)]  (2304 floats = 576 float4)
//   out[p]   = [reprs[pair_i[p]] | reprs[pair_j[p]]] (4608 floats = 1152 float4)
//
// Two-phase:
//   Phase 1: 4096 blocks x 192 threads -> reprs into d_ws (37.75 MB).
//   Phase 2: streaming gather-copy, 302 MB coalesced writes (the HBM bound).
//            Out-writes are NON-TEMPORAL: 302 MB write traffic > 256 MB L3;
//            allocating stores would sweep the Infinity Cache and evict the
//            38 MB reprs table between re-uses, turning the 302 MB of logical
//            gather reads into HBM fetches. nt stores keep reprs L3-resident.
//            2 pairs per iteration = 12 independent loads in flight.

#define SPAN_HF4  192          // H / 4 float4s
#define SPAN_TMAX 16
#define SPAN_SL   2048         // S * L
#define REPR_F4   576          // 3 * 192 float4 per span
#define OUT_F4    1152         // 2 * 576 float4 per pair

// Native clang vector type: __builtin_nontemporal_store requires a pointer to
// scalar or native vector (HIP_vector_type<float,4> is a struct and rejected).
typedef float f4nt __attribute__((ext_vector_type(4)));

__device__ __forceinline__ void nt_store_f4(const float4 v, float4* p) {
    f4nt t;
    t.x = v.x; t.y = v.y; t.z = v.z; t.w = v.w;
    __builtin_nontemporal_store(t, reinterpret_cast<f4nt*>(p));
}

__global__ __launch_bounds__(192)
void span_reprs_kernel(
    const float4* __restrict__ hidden,    // (B, SL, HF4)
    const int*    __restrict__ span_doc,
    const int*    __restrict__ span_tok,  // (N_SPANS, TMAX)
    const int*    __restrict__ span_len,
    float4*       __restrict__ reprs)     // (N_SPANS, 576)
{
    const int s = blockIdx.x;
    const int c = threadIdx.x;            // 0..191

    const int doc = span_doc[s];          // block-uniform
    const int len = span_len[s];
    const int* toks = span_tok + s * SPAN_TMAX;
    const float4* base = hidden + (size_t)doc * (SPAN_SL * SPAN_HF4);

    float4 first = make_float4(0.f, 0.f, 0.f, 0.f);
    float4 last  = make_float4(0.f, 0.f, 0.f, 0.f);
    float sx = 0.f, sy = 0.f, sz = 0.f, sw = 0.f;

    // Clamp index: loads beyond len-1 reload token len-1 (valid addr, L2-hit).
    // => 16 unconditional independent loads; `last` falls out for free.
    #pragma unroll
    for (int t = 0; t < SPAN_TMAX; ++t) {
        const int tc = (t < len) ? t : (len - 1);
        const float4 v = base[(size_t)toks[tc] * SPAN_HF4 + c];
        if (t == 0) first = v;            // uniform, compile-time peel
        last = v;
        const float m = (t < len) ? 1.f : 0.f;
        sx += v.x * m; sy += v.y * m; sz += v.z * m; sw += v.w * m;
    }

    const float inv = 1.0f / (float)len;
    float4* r = reprs + (size_t)s * REPR_F4;
    // Regular (allocating) stores on purpose: we WANT reprs resident in
    // L2/L3 for phase 2's gather.
    r[c]                = first;
    r[SPAN_HF4 + c]     = make_float4(sx * inv, sy * inv, sz * inv, sw * inv);
    r[2 * SPAN_HF4 + c] = last;
}

__global__ __launch_bounds__(192)
void span_pairs_kernel(
    const float4* __restrict__ reprs,     // (N_SPANS, 576)
    const int*    __restrict__ pair_i,
    const int*    __restrict__ pair_j,
    float4*       __restrict__ out,       // (N_PAIRS, 1152)
    int n_pairs)
{
    const int c = threadIdx.x;            // 0..191
    // 2 pairs per iteration: 12 independent gather loads in flight.
    for (int p = blockIdx.x * 2; p < n_pairs; p += gridDim.x * 2) {
        const int pA = p;
        const int pB = p + 1;
        const bool hasB = (pB < n_pairs);

        const int piA = pair_i[pA];
        const int pjA = pair_j[pA];
        const int piB = hasB ? pair_i[pB] : piA;
        const int pjB = hasB ? pair_j[pB] : pjA;

        const float4* riA = reprs + (size_t)piA * REPR_F4;
        const float4* rjA = reprs + (size_t)pjA * REPR_F4;
        const float4* riB = reprs + (size_t)piB * REPR_F4;
        const float4* rjB = reprs + (size_t)pjB * REPR_F4;

        // 12 independent loads (L3-hit once nt stores stop thrashing L3).
        const float4 a0 = riA[c];
        const float4 a1 = riA[SPAN_HF4 + c];
        const float4 a2 = riA[2 * SPAN_HF4 + c];
        const float4 b0 = rjA[c];
        const float4 b1 = rjA[SPAN_HF4 + c];
        const float4 b2 = rjA[2 * SPAN_HF4 + c];
        const float4 c0 = riB[c];
        const float4 c1 = riB[SPAN_HF4 + c];
        const float4 c2 = riB[2 * SPAN_HF4 + c];
        const float4 d0 = rjB[c];
        const float4 d1 = rjB[SPAN_HF4 + c];
        const float4 d2 = rjB[2 * SPAN_HF4 + c];

        // Non-temporal coalesced stores: do NOT allocate 302 MB of streaming
        // writes in L2/L3 (it would evict the reprs table mid-kernel).
        float4* oA = out + (size_t)pA * OUT_F4;
        nt_store_f4(a0, &oA[c]);
        nt_store_f4(a1, &oA[SPAN_HF4 + c]);
        nt_store_f4(a2, &oA[2 * SPAN_HF4 + c]);
        nt_store_f4(b0, &oA[3 * SPAN_HF4 + c]);
        nt_store_f4(b1, &oA[4 * SPAN_HF4 + c]);
        nt_store_f4(b2, &oA[5 * SPAN_HF4 + c]);

        if (hasB) {
            float4* oB = out + (size_t)pB * OUT_F4;
            nt_store_f4(c0, &oB[c]);
            nt_store_f4(c1, &oB[SPAN_HF4 + c]);
            nt_store_f4(c2, &oB[2 * SPAN_HF4 + c]);
            nt_store_f4(d0, &oB[3 * SPAN_HF4 + c]);
            nt_store_f4(d1, &oB[4 * SPAN_HF4 + c]);
            nt_store_f4(d2, &oB[5 * SPAN_HF4 + c]);
        }
    }
}

// Fallback single kernel (only used if ws_size is too small for reprs).
__global__ __launch_bounds__(192)
void span_fused_kernel(
    const float4* __restrict__ hidden,
    const int*    __restrict__ span_doc,
    const int*    __restrict__ span_tok,
    const int*    __restrict__ span_len,
    const int*    __restrict__ pair_i,
    const int*    __restrict__ pair_j,
    float4*       __restrict__ out)
{
    const int p = blockIdx.x;
    const int c = threadIdx.x;
    const int si = pair_i[p];
    const int sj = pair_j[p];
    float4* orow = out + (size_t)p * OUT_F4;

    #pragma unroll
    for (int side = 0; side < 2; ++side) {
        const int s   = side ? sj : si;
        const int doc = span_doc[s];
        const int len = span_len[s];
        const int* toks = span_tok + s * SPAN_TMAX;
        const float4* base = hidden + (size_t)doc * (SPAN_SL * SPAN_HF4);

        float4 first = make_float4(0.f, 0.f, 0.f, 0.f);
        float4 last  = make_float4(0.f, 0.f, 0.f, 0.f);
        float sx = 0.f, sy = 0.f, sz = 0.f, sw = 0.f;
        #pragma unroll
        for (int t = 0; t < SPAN_TMAX; ++t) {
            const int tc = (t < len) ? t : (len - 1);
            const float4 v = base[(size_t)toks[tc] * SPAN_HF4 + c];
            if (t == 0) first = v;
            last = v;
            const float m = (t < len) ? 1.f : 0.f;
            sx += v.x * m; sy += v.y * m; sz += v.z * m; sw += v.w * m;
        }
        const float inv = 1.0f / (float)len;
        float4* o = orow + side * REPR_F4;
        nt_store_f4(first, &o[c]);
        nt_store_f4(make_float4(sx * inv, sy * inv, sz * inv, sw * inv),
                    &o[SPAN_HF4 + c]);
        nt_store_f4(last, &o[2 * SPAN_HF4 + c]);
    }
}

extern "C" void kernel_launch(void* const* d_in, const int* in_sizes, int n_in,
                              void* d_out, int out_size, void* d_ws, size_t ws_size,
                              hipStream_t stream) {
    const float4* hidden  = (const float4*)d_in[0];
    const int* span_doc   = (const int*)d_in[1];
    const int* span_tok   = (const int*)d_in[2];
    const int* span_len   = (const int*)d_in[3];
    const int* pair_i     = (const int*)d_in[4];
    const int* pair_j     = (const int*)d_in[5];
    float4* out           = (float4*)d_out;

    const int n_spans = in_sizes[1];      // 4096
    const int n_pairs = in_sizes[4];      // 16384
    const size_t reprs_bytes = (size_t)n_spans * REPR_F4 * sizeof(float4);

    if (ws_size >= reprs_bytes) {
        float4* reprs = (float4*)d_ws;
        span_reprs_kernel<<<n_spans, 192, 0, stream>>>(
            hidden, span_doc, span_tok, span_len, reprs);
        // 4096 blocks, 2 pairs/iter, 2 iters each.
        span_pairs_kernel<<<4096, 192, 0, stream>>>(
            reprs, pair_i, pair_j, out, n_pairs);
    } else {
        span_fused_kernel<<<n_pairs, 192, 0, stream>>>(
            hidden, span_doc, span_tok, span_len, pair_i, pair_j, out);
    }
}

// Round 3
// 365.326 us; speedup vs baseline: 1.0696x; 1.0437x over previous
//
#include <hip/hip_runtime.h>

// Problem constants (from reference):
//   B=8, S=4, L=512, H=768  -> hidden (8, 2048, 768) fp32 (50 MB, L3-resident)
//   N_SPANS=4096, T_MAX=16, N_PAIRS=16384
//   reprs[s] = [first(768) | mean(768) | last(768)]  (2304 floats = 576 float4)
//   out[p]   = [reprs[pair_i[p]] | reprs[pair_j[p]]] (4608 floats = 1152 float4)
//
// R3 structure: SCATTER, not gather.
//   Old: phase1 writes reprs (38 MB), phase2 gathers 302 MB logical reads from
//        it + 302 MB writes. Two ~190 us passes.
//   New: build inverse map span -> [(pair,side)...] (32768 entries) with
//        3 tiny kernels (zero/count, scan, fill), then ONE main kernel:
//        compute [first|mean|last] in registers and nt-store it directly to
//        every (pair,side) slot. Eliminates the whole second pass, the 302 MB
//        logical re-read, and the 76 MB reprs HBM round-trip.
//   Out writes stay non-temporal: 302 MB streaming > 256 MB L3; don't evict
//   the 50 MB hidden table mid-kernel.

#define SPAN_HF4  192          // H / 4 float4s
#define SPAN_TMAX 16
#define SPAN_SL   2048         // S * L
#define REPR_F4   576          // 3 * 192 float4 per span
#define OUT_F4    1152         // 2 * 576 float4 per pair
#define MAX_SPANS 4096         // scan kernel capacity (1024 thr x 4)

// Native clang vector type: __builtin_nontemporal_store requires a pointer to
// scalar or native vector (HIP_vector_type<float,4> is a struct and rejected).
typedef float f4nt __attribute__((ext_vector_type(4)));

__device__ __forceinline__ void nt_store_f4(const float4 v, float4* p) {
    f4nt t;
    t.x = v.x; t.y = v.y; t.z = v.z; t.w = v.w;
    __builtin_nontemporal_store(t, reinterpret_cast<f4nt*>(p));
}

// ---------------------------------------------------------------- inverse map

__global__ void zero_counts_kernel(int* __restrict__ counts, int n) {
    const int i = blockIdx.x * blockDim.x + threadIdx.x;
    if (i < n) counts[i] = 0;
}

__global__ void count_uses_kernel(const int* __restrict__ pair_i,
                                  const int* __restrict__ pair_j,
                                  int* __restrict__ counts, int n_pairs) {
    const int p = blockIdx.x * blockDim.x + threadIdx.x;
    if (p < n_pairs) {
        atomicAdd(&counts[pair_i[p]], 1);
        atomicAdd(&counts[pair_j[p]], 1);
    }
}

// Single-block exclusive scan over <= 4096 counts (1024 threads x 4 elems).
__global__ __launch_bounds__(1024)
void scan_offsets_kernel(const int* __restrict__ counts,
                         int* __restrict__ offsets,   // n_spans+1 entries
                         int* __restrict__ cursor,    // n_spans entries
                         int n_spans) {
    __shared__ int sums[1024];
    const int t = threadIdx.x;
    const int base = t * 4;
    int c0 = 0, c1 = 0, c2 = 0, c3 = 0;
    if (base     < n_spans) c0 = counts[base];
    if (base + 1 < n_spans) c1 = counts[base + 1];
    if (base + 2 < n_spans) c2 = counts[base + 2];
    if (base + 3 < n_spans) c3 = counts[base + 3];
    const int local = c0 + c1 + c2 + c3;
    sums[t] = local;
    __syncthreads();
    // Hillis-Steele inclusive scan over the 1024 per-thread sums.
    for (int off = 1; off < 1024; off <<= 1) {
        const int v = (t >= off) ? sums[t - off] : 0;
        __syncthreads();
        sums[t] += v;
        __syncthreads();
    }
    const int excl = (t == 0) ? 0 : sums[t - 1];
    const int o0 = excl;
    const int o1 = o0 + c0;
    const int o2 = o1 + c1;
    const int o3 = o2 + c2;
    if (base     < n_spans) { offsets[base]     = o0; cursor[base]     = o0; }
    if (base + 1 < n_spans) { offsets[base + 1] = o1; cursor[base + 1] = o1; }
    if (base + 2 < n_spans) { offsets[base + 2] = o2; cursor[base + 2] = o2; }
    if (base + 3 < n_spans) { offsets[base + 3] = o3; cursor[base + 3] = o3; }
    if (t == 1023) offsets[n_spans] = sums[1023];   // total = 2*n_pairs
}

__global__ void fill_targets_kernel(const int* __restrict__ pair_i,
                                    const int* __restrict__ pair_j,
                                    int* __restrict__ cursor,
                                    int* __restrict__ targets,  // 2*n_pairs
                                    int n_pairs) {
    const int p = blockIdx.x * blockDim.x + threadIdx.x;
    if (p < n_pairs) {
        const int a = atomicAdd(&cursor[pair_i[p]], 1);
        targets[a] = p * 2;          // side 0 (i-half)
        const int b = atomicAdd(&cursor[pair_j[p]], 1);
        targets[b] = p * 2 + 1;      // side 1 (j-half)
    }
}

// ------------------------------------------------------------------ main pass

__global__ __launch_bounds__(192)
void span_scatter_kernel(
    const float4* __restrict__ hidden,    // (B, SL, HF4)
    const int*    __restrict__ span_doc,
    const int*    __restrict__ span_tok,  // (N_SPANS, TMAX)
    const int*    __restrict__ span_len,
    const int*    __restrict__ offsets,   // (n_spans+1)
    const int*    __restrict__ targets,   // (2*n_pairs): p*2+side
    float4*       __restrict__ out)       // (N_PAIRS, 1152)
{
    const int s = blockIdx.x;
    const int c = threadIdx.x;            // 0..191

    const int doc = span_doc[s];          // block-uniform
    const int len = span_len[s];
    const int* toks = span_tok + s * SPAN_TMAX;
    const float4* base = hidden + (size_t)doc * (SPAN_SL * SPAN_HF4);

    float4 first = make_float4(0.f, 0.f, 0.f, 0.f);
    float4 last  = make_float4(0.f, 0.f, 0.f, 0.f);
    float sx = 0.f, sy = 0.f, sz = 0.f, sw = 0.f;

    // Clamp index: loads beyond len-1 reload token len-1 (valid addr, cached).
    // => 16 unconditional independent loads; `last` falls out for free.
    #pragma unroll
    for (int t = 0; t < SPAN_TMAX; ++t) {
        const int tc = (t < len) ? t : (len - 1);
        const float4 v = base[(size_t)toks[tc] * SPAN_HF4 + c];
        if (t == 0) first = v;            // uniform, compile-time peel
        last = v;
        const float m = (t < len) ? 1.f : 0.f;
        sx += v.x * m; sy += v.y * m; sz += v.z * m; sw += v.w * m;
    }

    const float inv = 1.0f / (float)len;
    const float4 a0 = first;
    const float4 a1 = make_float4(sx * inv, sy * inv, sz * inv, sw * inv);
    const float4 a2 = last;

    // Scatter this span's repr to every (pair,side) slot referencing it.
    // Targets staged through LDS in chunks so the uniform loads are parallel,
    // and robust to arbitrarily popular spans.
    __shared__ int tgt[192];
    const int start = offsets[s];
    const int end   = offsets[s + 1];
    for (int cb = start; cb < end; cb += 192) {
        const int n = min(192, end - cb);
        if (c < n) tgt[c] = targets[cb + c];
        __syncthreads();
        for (int k = 0; k < n; ++k) {
            const int tv = tgt[k];        // block-uniform
            float4* o = out + (size_t)(tv >> 1) * OUT_F4
                            + (size_t)(tv & 1) * REPR_F4;
            nt_store_f4(a0, &o[c]);
            nt_store_f4(a1, &o[SPAN_HF4 + c]);
            nt_store_f4(a2, &o[2 * SPAN_HF4 + c]);
        }
        __syncthreads();
    }
}

// ------------------------------------------- fallback (no workspace needed)

__global__ __launch_bounds__(192)
void span_fused_kernel(
    const float4* __restrict__ hidden,
    const int*    __restrict__ span_doc,
    const int*    __restrict__ span_tok,
    const int*    __restrict__ span_len,
    const int*    __restrict__ pair_i,
    const int*    __restrict__ pair_j,
    float4*       __restrict__ out)
{
    const int p = blockIdx.x;
    const int c = threadIdx.x;
    const int si = pair_i[p];
    const int sj = pair_j[p];
    float4* orow = out + (size_t)p * OUT_F4;

    #pragma unroll
    for (int side = 0; side < 2; ++side) {
        const int s   = side ? sj : si;
        const int doc = span_doc[s];
        const int len = span_len[s];
        const int* toks = span_tok + s * SPAN_TMAX;
        const float4* base = hidden + (size_t)doc * (SPAN_SL * SPAN_HF4);

        float4 first = make_float4(0.f, 0.f, 0.f, 0.f);
        float4 last  = make_float4(0.f, 0.f, 0.f, 0.f);
        float sx = 0.f, sy = 0.f, sz = 0.f, sw = 0.f;
        #pragma unroll
        for (int t = 0; t < SPAN_TMAX; ++t) {
            const int tc = (t < len) ? t : (len - 1);
            const float4 v = base[(size_t)toks[tc] * SPAN_HF4 + c];
            if (t == 0) first = v;
            last = v;
            const float m = (t < len) ? 1.f : 0.f;
            sx += v.x * m; sy += v.y * m; sz += v.z * m; sw += v.w * m;
        }
        const float inv = 1.0f / (float)len;
        float4* o = orow + side * REPR_F4;
        nt_store_f4(first, &o[c]);
        nt_store_f4(make_float4(sx * inv, sy * inv, sz * inv, sw * inv),
                    &o[SPAN_HF4 + c]);
        nt_store_f4(last, &o[2 * SPAN_HF4 + c]);
    }
}

// ----------------------------------------------------------------- launcher

extern "C" void kernel_launch(void* const* d_in, const int* in_sizes, int n_in,
                              void* d_out, int out_size, void* d_ws, size_t ws_size,
                              hipStream_t stream) {
    const float4* hidden  = (const float4*)d_in[0];
    const int* span_doc   = (const int*)d_in[1];
    const int* span_tok   = (const int*)d_in[2];
    const int* span_len   = (const int*)d_in[3];
    const int* pair_i     = (const int*)d_in[4];
    const int* pair_j     = (const int*)d_in[5];
    float4* out           = (float4*)d_out;

    const int n_spans = in_sizes[1];      // 4096
    const int n_pairs = in_sizes[4];      // 16384

    // Workspace layout (16B-aligned sections):
    //   counts  : n_spans ints
    //   offsets : n_spans+1 ints
    //   cursor  : n_spans ints
    //   targets : 2*n_pairs ints
    auto align16 = [](size_t x) { return (x + 15) & ~(size_t)15; };
    const size_t counts_b  = align16((size_t)n_spans * sizeof(int));
    const size_t offsets_b = align16((size_t)(n_spans + 1) * sizeof(int));
    const size_t cursor_b  = align16((size_t)n_spans * sizeof(int));
    const size_t targets_b = align16((size_t)2 * n_pairs * sizeof(int));
    const size_t need = counts_b + offsets_b + cursor_b + targets_b;

    if (n_spans <= MAX_SPANS && ws_size >= need) {
        char* ws = (char*)d_ws;
        int* counts  = (int*)(ws);
        int* offsets = (int*)(ws + counts_b);
        int* cursor  = (int*)(ws + counts_b + offsets_b);
        int* targets = (int*)(ws + counts_b + offsets_b + cursor_b);

        const int zb = (n_spans + 255) / 256;
        const int pb = (n_pairs + 255) / 256;
        zero_counts_kernel<<<zb, 256, 0, stream>>>(counts, n_spans);
        count_uses_kernel<<<pb, 256, 0, stream>>>(pair_i, pair_j, counts, n_pairs);
        scan_offsets_kernel<<<1, 1024, 0, stream>>>(counts, offsets, cursor, n_spans);
        fill_targets_kernel<<<pb, 256, 0, stream>>>(pair_i, pair_j, cursor, targets, n_pairs);
        span_scatter_kernel<<<n_spans, 192, 0, stream>>>(
            hidden, span_doc, span_tok, span_len, offsets, targets, out);
    } else {
        span_fused_kernel<<<n_pairs, 192, 0, stream>>>(
            hidden, span_doc, span_tok, span_len, pair_i, pair_j, out);
    }
}